// Round 10
// baseline (322.202 us; speedup 1.0000x reference)
//
#include <hip/hip_runtime.h>

#define B_    32
#define N_    512
#define D_    128
#define ROWS  (B_ * N_)          // 16384
// 1/sqrt(32) * log2(e): folded into q at qkv time so attn uses exp2 directly
#define SCALE2_ (0.17677669529663687f * 1.4426950408889634f)

typedef __bf16 bf16x8 __attribute__((ext_vector_type(8)));
typedef __bf16 bf16x4 __attribute__((ext_vector_type(4)));
typedef float  f32x4  __attribute__((ext_vector_type(4)));

static __device__ __forceinline__ f32x4 mfma16(bf16x8 a, bf16x8 b, f32x4 c) {
  return __builtin_amdgcn_mfma_f32_16x16x32_bf16(a, b, c, 0, 0, 0);
}

// ---------------------------------------------------------------------------
// Prep: mask bit-pack (BW-bound) + weight transposes. (unchanged from R5)
// ---------------------------------------------------------------------------
__global__ __launch_bounds__(256) void prep_kernel(
    const int* __restrict__ m00, const int* __restrict__ m01,
    const int* __restrict__ m10, const int* __restrict__ m11,
    const float* __restrict__ wq0, const float* __restrict__ wk0, const float* __restrict__ wv0,
    const float* __restrict__ wq1, const float* __restrict__ wk1, const float* __restrict__ wv1,
    const float* __restrict__ wo00, const float* __restrict__ wo01,
    const float* __restrict__ wo10, const float* __restrict__ wo11,
    const float* __restrict__ wf0, const float* __restrict__ wf1,
    __bf16* __restrict__ wtb, __bf16* __restrict__ wob, __bf16* __restrict__ wfb,
    unsigned long long* __restrict__ mpk)
{
  const int bx = blockIdx.x, t = threadIdx.x;
  if (bx < 16384) {
    const int wid = bx * 4 + (t >> 6);
    const int lane = t & 63;
    const int row = wid & 511, b = (wid >> 9) & 31, a = wid >> 14;
    const int* msel = (a == 0) ? m00 : (a == 1) ? m11 : (a == 2) ? m01 : m10;
    const int* src = msel + ((size_t)b * N_ + row) * N_;
    unsigned long long mine = 0;
    #pragma unroll
    for (int ch = 0; ch < 8; ++ch) {
      const int v = src[ch * 64 + lane];           // coalesced 256 B per load
      const unsigned long long bits = __ballot(v != 0);
      if (lane == ch) mine = bits;
    }
    if (lane < 8)
      mpk[((size_t)(a * 32 + b) * 8 + lane) * 512 + row] = mine;
  } else if (bx < 16480) {
    const int i = bx - 16384, mat = i >> 4, sub = i & 15;
    const float* w = (mat == 0) ? wq0 : (mat == 1) ? wk0 : (mat == 2) ? wv0
                   : (mat == 3) ? wq1 : (mat == 4) ? wk1 : wv1;
    __bf16* dst = wtb + mat * 16384;
    const int fidx = sub * 256 + t;                // 0..4095 float4s
    const float4 f = ((const float4*)w)[fidx];
    const int e = fidx * 4, k = e >> 7, n = e & 127;
    dst[(n + 0) * 128 + k] = (__bf16)f.x;
    dst[(n + 1) * 128 + k] = (__bf16)f.y;
    dst[(n + 2) * 128 + k] = (__bf16)f.z;
    dst[(n + 3) * 128 + k] = (__bf16)f.w;
  } else if (bx < 16496) {
    const int i = bx - 16480, a = i >> 2, sub = i & 3;
    const float* w = (a == 0) ? wo00 : (a == 1) ? wo11 : (a == 2) ? wo01 : wo10;
    __bf16* dst = wob + a * 4096;
    const int fidx = sub * 256 + t;                // 0..1023 float4s
    const float4 f = ((const float4*)w)[fidx];
    const int e = fidx * 4, k = e >> 5, n = e & 31;
    dst[(n + 0) * 128 + k] = (__bf16)f.x;
    dst[(n + 1) * 128 + k] = (__bf16)f.y;
    dst[(n + 2) * 128 + k] = (__bf16)f.z;
    dst[(n + 3) * 128 + k] = (__bf16)f.w;
  } else {
    const int i = bx - 16496, g = i >> 3, sub = i & 7;
    const float* w = g ? wf1 : wf0;                // [64][128]
    __bf16* dst = wfb + g * 8192;                  // [n 128][k 64]
    const int d0 = sub * 1024 + t * 4;             // 4 consecutive k, same n
    const int n = d0 >> 6, k = d0 & 63;
    bf16x4 v;
    #pragma unroll
    for (int j = 0; j < 4; ++j) v[j] = (__bf16)w[(size_t)(k + j) * 128 + n];
    *(bf16x4*)&dst[d0] = v;
  }
}

// ---------------------------------------------------------------------------
// Kernel 2: q/k/v = relu(x @ w + b), bf16. Block = (matrix mat 0..5, 64-row
// tile). q pre-scaled by SCALE2. q,k stored [row][128]; v transposed
// vt[b][dim][key].
// ---------------------------------------------------------------------------
__global__ __launch_bounds__(256) void qkv_kernel(
    const float* __restrict__ x0, const float* __restrict__ x1,
    const float* __restrict__ bq0, const float* __restrict__ bk0, const float* __restrict__ bv0,
    const float* __restrict__ bq1, const float* __restrict__ bk1, const float* __restrict__ bv1,
    const __bf16* __restrict__ wtb, __bf16* __restrict__ qkvb)
{
  __shared__ __align__(16) __bf16 vtile[128][72];
  const int bx = blockIdx.x;
  const int mat = bx >> 8, tile = bx & 255, R0 = tile * 64;
  const int m = mat % 3;
  const int t = threadIdx.x, lane = t & 63, wave = t >> 6;
  const int quad = lane >> 4, ln = lane & 15;
  const float* xs = (mat < 3) ? x0 : x1;
  const float* bias = (mat == 0) ? bq0 : (mat == 1) ? bk0 : (mat == 2) ? bv0
                    : (mat == 3) ? bq1 : (mat == 4) ? bk1 : bv1;
  const __bf16* wt = wtb + mat * 16384;
  __bf16* outp = qkvb + (size_t)mat * (ROWS * D_);

  bf16x8 af[4];
  {
    const int row = R0 + wave * 16 + ln;
    #pragma unroll
    for (int ks = 0; ks < 4; ++ks) {
      const float4* xp = (const float4*)(xs + (size_t)row * D_ + ks * 32 + quad * 8);
      float4 a = xp[0], b = xp[1];
      bf16x8 v;
      v[0] = (__bf16)a.x; v[1] = (__bf16)a.y; v[2] = (__bf16)a.z; v[3] = (__bf16)a.w;
      v[4] = (__bf16)b.x; v[5] = (__bf16)b.y; v[6] = (__bf16)b.z; v[7] = (__bf16)b.w;
      af[ks] = v;
    }
  }
  const f32x4 zero4 = {0.f, 0.f, 0.f, 0.f};

  f32x4 acc[8];
  #pragma unroll
  for (int nt = 0; nt < 8; ++nt) acc[nt] = zero4;
  #pragma unroll
  for (int ks = 0; ks < 4; ++ks) {
    #pragma unroll
    for (int nt = 0; nt < 8; ++nt) {
      bf16x8 bfrag = *(const bf16x8*)(wt + (size_t)(nt * 16 + ln) * D_ + ks * 32 + quad * 8);
      acc[nt] = mfma16(af[ks], bfrag, acc[nt]);
    }
  }

  if (m != 2) {
    const float sc = (m == 0) ? SCALE2_ : 1.0f;
    #pragma unroll
    for (int nt = 0; nt < 8; ++nt) {
      const int col = nt * 16 + ln;
      const float bv = bias[col];
      #pragma unroll
      for (int r = 0; r < 4; ++r) {
        float v = fmaxf(acc[nt][r] + bv, 0.f) * sc;
        outp[(size_t)(R0 + wave * 16 + quad * 4 + r) * D_ + col] = (__bf16)v;
      }
    }
  } else {
    #pragma unroll
    for (int nt = 0; nt < 8; ++nt) {
      const int col = nt * 16 + ln;
      const float bv = bias[col];
      #pragma unroll
      for (int r = 0; r < 4; ++r) {
        float v = fmaxf(acc[nt][r] + bv, 0.f);
        vtile[col][wave * 16 + quad * 4 + r] = (__bf16)v;
      }
    }
    __syncthreads();
    const int b = R0 >> 9, kb2 = R0 & 511;
    const int dim = t >> 1, off = (t & 1) * 32;
    uint4* dst = (uint4*)(outp + (size_t)b * (D_ * N_) + (size_t)dim * N_ + kb2 + off);
    const uint4* srcp = (const uint4*)&vtile[dim][off];
    #pragma unroll
    for (int i = 0; i < 4; ++i) dst[i] = srcp[i];
  }
}

// ---------------------------------------------------------------------------
// Kernel 3: fused masked attention + wo projection + relu.
// 32 q-rows per block (qt 0..15), grid 2048 — 2x blocks, half per-wave work
// vs R9 for more TLP. wave = head h. Key-permuted register pipeline (R9):
// tile `at` covers keys kappa = 32*(at>>1) + 8*quad + 4*(at&1) + r, so the
// S^T C-fragment IS the PV B-fragment — no LDS/barriers/shuffles in K-loop.
// bx decode keeps all 16 q-tile blocks of a combo on one XCD (bx%8).
// ---------------------------------------------------------------------------
__global__ __launch_bounds__(256, 2) void attn_kernel(
    const __bf16* __restrict__ qkvb,
    const unsigned long long* __restrict__ mpk,
    const __bf16* __restrict__ wob,
    const float* __restrict__ bo00, const float* __restrict__ bo01,
    const float* __restrict__ bo10, const float* __restrict__ bo11,
    __bf16* __restrict__ projb)
{
  __shared__ __align__(16) __bf16 OL[32][136];   // epilogue O staging (8704 B)

  const int bx = blockIdx.x;
  const int qt = bx >> 7, cb = bx & 127, a = cb >> 5, b = cb & 31;
  const int t = threadIdx.x, lane = t & 63, h = t >> 6;
  const int quad = lane >> 4, ln = lane & 15;

  const int qg = (a == 1 || a == 3) ? 1 : 0;
  const int kg = (a == 1 || a == 2) ? 1 : 0;
  const float* bo = (a == 0) ? bo00 : (a == 1) ? bo11 : (a == 2) ? bo01 : bo10;

  const __bf16* qb  = qkvb + (size_t)(qg * 3 + 0) * (ROWS * D_) + (size_t)(b * N_ + qt * 32) * D_;
  const __bf16* kb  = qkvb + (size_t)(kg * 3 + 1) * (ROWS * D_) + (size_t)b * N_ * D_;
  const __bf16* vtb = qkvb + (size_t)(kg * 3 + 2) * (ROWS * D_) + (size_t)b * D_ * N_;
  const unsigned long long* mrow = mpk + (size_t)(a * 32 + b) * 8 * 512 + qt * 32;

  // permuted tile-local key row for K loads (position p=ln within a tile)
  const int lnoff = 8 * (ln >> 2) + (ln & 3);

  // Q as MFMA-B fragments (persistent): n = qrow = ln, k = dim quad*8+j
  bf16x8 qf[2];
  #pragma unroll
  for (int bt = 0; bt < 2; ++bt)
    qf[bt] = *(const bf16x8*)(qb + (size_t)(bt * 16 + ln) * D_ + h * 32 + quad * 8);

  const f32x4 zero4 = {0.f, 0.f, 0.f, 0.f};
  f32x4 Oacc[2][2];
  float lp[2];
  #pragma unroll
  for (int bt = 0; bt < 2; ++bt) {
    lp[bt] = 0.f;
    Oacc[0][bt] = zero4; Oacc[1][bt] = zero4;
  }

  unsigned long long mb[2];
  #pragma unroll
  for (int bt = 0; bt < 2; ++bt) mb[bt] = mrow[bt * 16 + ln];

  for (int ch = 0; ch < 8; ++ch) {
    const int kc = ch * 64;

    // prefetch next chunk's mask bits (L2/L3-resident, 2x8B)
    unsigned long long mbn[2] = {0, 0};
    if (ch < 7) {
      #pragma unroll
      for (int bt = 0; bt < 2; ++bt)
        mbn[bt] = mrow[(size_t)(ch + 1) * 512 + bt * 16 + ln];
    }

    // S^T tiles with permuted keys; P kept in registers.
    bf16x4 pregs[4][2];   // [at][bt]
    #pragma unroll
    for (int at = 0; at < 4; ++at) {
      const int kconst = 32 * (at >> 1) + 4 * (at & 1);   // tile key base bits
      bf16x8 kf = *(const bf16x8*)(kb + (size_t)(kc + kconst + lnoff) * D_ + h * 32 + quad * 8);
      #pragma unroll
      for (int bt = 0; bt < 2; ++bt) {
        f32x4 s = mfma16(kf, qf[bt], zero4);
        bf16x4 pv;
        float ps = 0.f;
        #pragma unroll
        for (int r = 0; r < 4; ++r) {
          // global key for (at, quad, r) = kconst + 8*quad + r
          const int bit = (int)((mb[bt] >> (kconst + 8 * quad + r)) & 1ull);
          const float p = bit ? __builtin_amdgcn_exp2f(s[r]) : 0.f;
          ps += p;
          pv[r] = (__bf16)p;
        }
        lp[bt] += ps;
        pregs[at][bt] = pv;
      }
    }

    // O^T += V^T . P^T — P fragments come straight from registers.
    #pragma unroll
    for (int s2 = 0; s2 < 2; ++s2) {
      bf16x8 pb[2];
      #pragma unroll
      for (int bt = 0; bt < 2; ++bt) {
        #pragma unroll
        for (int j = 0; j < 4; ++j) {
          pb[bt][j]     = pregs[2 * s2][bt][j];
          pb[bt][4 + j] = pregs[2 * s2 + 1][bt][j];
        }
      }
      #pragma unroll
      for (int d = 0; d < 2; ++d) {
        bf16x8 vf = *(const bf16x8*)(vtb + (size_t)(h * 32 + d * 16 + ln) * N_ + kc + s2 * 32 + quad * 8);
        #pragma unroll
        for (int bt = 0; bt < 2; ++bt)
          Oacc[d][bt] = mfma16(vf, pb[bt], Oacc[d][bt]);
      }
    }

    #pragma unroll
    for (int bt = 0; bt < 2; ++bt) mb[bt] = mbn[bt];
  }

  float fac[2];
  #pragma unroll
  for (int bt = 0; bt < 2; ++bt) {
    float l = lp[bt] + __shfl_xor(lp[bt], 16);
    l += __shfl_xor(l, 32);
    fac[bt] = (l > 0.f) ? 1.f / l : 0.f;   // l==0: fully-masked row -> 0 (gated)
  }

  // epilogue: O^T regs -> LDS O[row][dim] (packed b64), then wo MFMA
  #pragma unroll
  for (int d = 0; d < 2; ++d)
    #pragma unroll
    for (int bt = 0; bt < 2; ++bt) {
      bf16x4 ov;
      #pragma unroll
      for (int r = 0; r < 4; ++r) ov[r] = (__bf16)(Oacc[d][bt][r] * fac[bt]);
      *(bf16x4*)&OL[bt * 16 + ln][h * 32 + d * 16 + quad * 4] = ov;
    }
  __syncthreads();

  // wo projection: wave w covers (row-tile = w>>1, ct = w&1); K=128
  const __bf16* wo = wob + a * 4096;   // [n 32][k 128]
  const int rt = h >> 1, ct = h & 1;
  f32x4 pacc = zero4;
  #pragma unroll
  for (int ks = 0; ks < 4; ++ks) {
    bf16x8 afr = *(const bf16x8*)&OL[rt * 16 + ln][ks * 32 + quad * 8];
    bf16x8 bw = *(const bf16x8*)(wo + (size_t)(ct * 16 + ln) * D_ + ks * 32 + quad * 8);
    pacc = mfma16(afr, bw, pacc);
  }
  const int R0g = b * N_ + qt * 32;
  const int col = ct * 16 + ln;
  const float bv = bo[col];
  #pragma unroll
  for (int r = 0; r < 4; ++r) {
    const float v = fmaxf(pacc[r] + bv, 0.f);
    projb[(size_t)(a * ROWS + R0g + rt * 16 + quad * 4 + r) * 32 + col] = (__bf16)v;
  }
}

// ---------------------------------------------------------------------------
// Kernel 4: out_g = concat(inner_g, inter_g) @ wf_g + bf_g  (MFMA, no LDS)
// grid 512: g = bx>>8, 64-row tile = bx&255; wave = 16-row tile.
// ---------------------------------------------------------------------------
__global__ __launch_bounds__(256) void outproj_kernel(
    const __bf16* __restrict__ projb, const __bf16* __restrict__ wfb,
    const float* __restrict__ bf0, const float* __restrict__ bf1,
    float* __restrict__ out)
{
  const int bx = blockIdx.x;
  const int g = bx >> 8, tile = bx & 255;
  const int t = threadIdx.x, lane = t & 63, w = t >> 6;
  const int quad = lane >> 4, ln = lane & 15;
  const int row = tile * 64 + w * 16;
  const f32x4 zero4 = {0.f, 0.f, 0.f, 0.f};

  const float* bfp = g ? bf1 : bf0;
  f32x4 acc[8];
  #pragma unroll
  for (int ct = 0; ct < 8; ++ct) acc[ct] = zero4;
  #pragma unroll
  for (int s = 0; s < 2; ++s) {
    const int asrc = s ? (2 + g) : g;
    bf16x8 afr = *(const bf16x8*)(projb + (size_t)(asrc * ROWS + row + ln) * 32 + quad * 8);
    const __bf16* wb = wfb + g * 8192 + s * 32;
    #pragma unroll
    for (int ct = 0; ct < 8; ++ct) {
      bf16x8 bw = *(const bf16x8*)(wb + (size_t)(ct * 16 + ln) * 64 + quad * 8);
      acc[ct] = mfma16(afr, bw, acc[ct]);
    }
  }
  float* og = out + (size_t)g * (ROWS * D_);
  #pragma unroll
  for (int ct = 0; ct < 8; ++ct) {
    const int col = ct * 16 + ln;
    const float bv = bfp[col];
    #pragma unroll
    for (int r = 0; r < 4; ++r)
      og[(size_t)(row + quad * 4 + r) * D_ + col] = acc[ct][r] + bv;
  }
}

// ---------------------------------------------------------------------------
extern "C" void kernel_launch(void* const* d_in, const int* in_sizes, int n_in,
                              void* d_out, int out_size, void* d_ws, size_t ws_size,
                              hipStream_t stream)
{
  const float* x0 = (const float*)d_in[0];
  const float* x1 = (const float*)d_in[1];
  const int* m00 = (const int*)d_in[2];
  const int* m01 = (const int*)d_in[3];
  const int* m10 = (const int*)d_in[4];
  const int* m11 = (const int*)d_in[5];
  const float* wq0 = (const float*)d_in[6];  const float* bq0 = (const float*)d_in[7];
  const float* wk0 = (const float*)d_in[8];  const float* bk0 = (const float*)d_in[9];
  const float* wv0 = (const float*)d_in[10]; const float* bv0 = (const float*)d_in[11];
  const float* wq1 = (const float*)d_in[12]; const float* bq1 = (const float*)d_in[13];
  const float* wk1 = (const float*)d_in[14]; const float* bk1 = (const float*)d_in[15];
  const float* wv1 = (const float*)d_in[16]; const float* bv1 = (const float*)d_in[17];
  const float* wo00 = (const float*)d_in[18]; const float* bo00 = (const float*)d_in[19];
  const float* wo01 = (const float*)d_in[20]; const float* bo01 = (const float*)d_in[21];
  const float* wo10 = (const float*)d_in[22]; const float* bo10 = (const float*)d_in[23];
  const float* wo11 = (const float*)d_in[24]; const float* bo11 = (const float*)d_in[25];
  const float* wf0 = (const float*)d_in[26]; const float* bf0 = (const float*)d_in[27];
  const float* wf1 = (const float*)d_in[28]; const float* bf1 = (const float*)d_in[29];

  // workspace layout (bytes):
  //   qkvb  @ 0        : 6 * 16384*128 * 2 = 25165824
  //   projb @ 25165824 : 4 * 16384*32 * 2  =  4194304
  //   wtb   @ 29360128 : 6 * 128*128 * 2   =   196608
  //   wob   @ 29556736 : 4 * 32*128 * 2    =    32768
  //   wfb   @ 29589504 : 2 * 128*64 * 2    =    32768
  //   mpk   @ 29622272 : 4*32*8*512 * 8    =  4194304   (total ~33.8 MB)
  __bf16* qkvb = (__bf16*)d_ws;
  __bf16* projb = (__bf16*)((char*)d_ws + 25165824);
  __bf16* wtb  = (__bf16*)((char*)d_ws + 29360128);
  __bf16* wob  = (__bf16*)((char*)d_ws + 29556736);
  __bf16* wfb  = (__bf16*)((char*)d_ws + 29589504);
  unsigned long long* mpk = (unsigned long long*)((char*)d_ws + 29622272);

  prep_kernel<<<dim3(16512), dim3(256), 0, stream>>>(
      m00, m01, m10, m11, wq0, wk0, wv0, wq1, wk1, wv1,
      wo00, wo01, wo10, wo11, wf0, wf1, wtb, wob, wfb, mpk);
  qkv_kernel<<<dim3(1536), dim3(256), 0, stream>>>(
      x0, x1, bq0, bk0, bv0, bq1, bk1, bv1, wtb, qkvb);
  attn_kernel<<<dim3(2048), dim3(256), 0, stream>>>(
      qkvb, mpk, wob, bo00, bo01, bo10, bo11, projb);
  outproj_kernel<<<dim3(512), dim3(256), 0, stream>>>(
      projb, wfb, bf0, bf1, (float*)d_out);
}

// Round 11
// 301.255 us; speedup vs baseline: 1.0695x; 1.0695x over previous
//
#include <hip/hip_runtime.h>

#define B_    32
#define N_    512
#define D_    128
#define ROWS  (B_ * N_)          // 16384
// 1/sqrt(32) * log2(e): folded into q at qkv time so attn uses exp2 directly
#define SCALE2_ (0.17677669529663687f * 1.4426950408889634f)

typedef __bf16 bf16x8 __attribute__((ext_vector_type(8)));
typedef __bf16 bf16x4 __attribute__((ext_vector_type(4)));
typedef float  f32x4  __attribute__((ext_vector_type(4)));

static __device__ __forceinline__ f32x4 mfma16(bf16x8 a, bf16x8 b, f32x4 c) {
  return __builtin_amdgcn_mfma_f32_16x16x32_bf16(a, b, c, 0, 0, 0);
}

// ---------------------------------------------------------------------------
// Prep: mask bit-pack (BW-bound) + weight transposes.
// blocks [0,16384): one wave per (a,b,row): 8 coalesced 256-B row-chunk loads
//   + 8 ballots -> mpk[((a*32+b)*8+ch)*512 + row], bit i = mask[row][ch*64+i].
//   a0=m00, a1=m11, a2=m01, a3=m10.
// blocks [16384,16480): wtb[mat][n][k] = bf16(w[k][n])  (96 blocks, float4)
// blocks [16480,16496): wob[a][n][k]   = bf16(wo[k][n]) (16 blocks)
// blocks [16496,16512): wfb[g][n][k]   = bf16(wf[k][n]) (16 blocks)
// ---------------------------------------------------------------------------
__global__ __launch_bounds__(256) void prep_kernel(
    const int* __restrict__ m00, const int* __restrict__ m01,
    const int* __restrict__ m10, const int* __restrict__ m11,
    const float* __restrict__ wq0, const float* __restrict__ wk0, const float* __restrict__ wv0,
    const float* __restrict__ wq1, const float* __restrict__ wk1, const float* __restrict__ wv1,
    const float* __restrict__ wo00, const float* __restrict__ wo01,
    const float* __restrict__ wo10, const float* __restrict__ wo11,
    const float* __restrict__ wf0, const float* __restrict__ wf1,
    __bf16* __restrict__ wtb, __bf16* __restrict__ wob, __bf16* __restrict__ wfb,
    unsigned long long* __restrict__ mpk)
{
  const int bx = blockIdx.x, t = threadIdx.x;
  if (bx < 16384) {
    const int wid = bx * 4 + (t >> 6);
    const int lane = t & 63;
    const int row = wid & 511, b = (wid >> 9) & 31, a = wid >> 14;
    const int* msel = (a == 0) ? m00 : (a == 1) ? m11 : (a == 2) ? m01 : m10;
    const int* src = msel + ((size_t)b * N_ + row) * N_;
    unsigned long long mine = 0;
    #pragma unroll
    for (int ch = 0; ch < 8; ++ch) {
      const int v = src[ch * 64 + lane];           // coalesced 256 B per load
      const unsigned long long bits = __ballot(v != 0);
      if (lane == ch) mine = bits;
    }
    if (lane < 8)
      mpk[((size_t)(a * 32 + b) * 8 + lane) * 512 + row] = mine;
  } else if (bx < 16480) {
    const int i = bx - 16384, mat = i >> 4, sub = i & 15;
    const float* w = (mat == 0) ? wq0 : (mat == 1) ? wk0 : (mat == 2) ? wv0
                   : (mat == 3) ? wq1 : (mat == 4) ? wk1 : wv1;
    __bf16* dst = wtb + mat * 16384;
    const int fidx = sub * 256 + t;                // 0..4095 float4s
    const float4 f = ((const float4*)w)[fidx];
    const int e = fidx * 4, k = e >> 7, n = e & 127;
    dst[(n + 0) * 128 + k] = (__bf16)f.x;
    dst[(n + 1) * 128 + k] = (__bf16)f.y;
    dst[(n + 2) * 128 + k] = (__bf16)f.z;
    dst[(n + 3) * 128 + k] = (__bf16)f.w;
  } else if (bx < 16496) {
    const int i = bx - 16480, a = i >> 2, sub = i & 3;
    const float* w = (a == 0) ? wo00 : (a == 1) ? wo11 : (a == 2) ? wo01 : wo10;
    __bf16* dst = wob + a * 4096;
    const int fidx = sub * 256 + t;                // 0..1023 float4s
    const float4 f = ((const float4*)w)[fidx];
    const int e = fidx * 4, k = e >> 5, n = e & 31;
    dst[(n + 0) * 128 + k] = (__bf16)f.x;
    dst[(n + 1) * 128 + k] = (__bf16)f.y;
    dst[(n + 2) * 128 + k] = (__bf16)f.z;
    dst[(n + 3) * 128 + k] = (__bf16)f.w;
  } else {
    const int i = bx - 16496, g = i >> 3, sub = i & 7;
    const float* w = g ? wf1 : wf0;                // [64][128]
    __bf16* dst = wfb + g * 8192;                  // [n 128][k 64]
    const int d0 = sub * 1024 + t * 4;             // 4 consecutive k, same n
    const int n = d0 >> 6, k = d0 & 63;
    bf16x4 v;
    #pragma unroll
    for (int j = 0; j < 4; ++j) v[j] = (__bf16)w[(size_t)(k + j) * 128 + n];
    *(bf16x4*)&dst[d0] = v;
  }
}

// ---------------------------------------------------------------------------
// Kernel 2: q/k/v = relu(x @ w + b), bf16. Block = (matrix mat 0..5, 64-row
// tile). q pre-scaled by SCALE2. q,k stored [row][128]; v transposed
// vt[b][dim][key].
// ---------------------------------------------------------------------------
__global__ __launch_bounds__(256) void qkv_kernel(
    const float* __restrict__ x0, const float* __restrict__ x1,
    const float* __restrict__ bq0, const float* __restrict__ bk0, const float* __restrict__ bv0,
    const float* __restrict__ bq1, const float* __restrict__ bk1, const float* __restrict__ bv1,
    const __bf16* __restrict__ wtb, __bf16* __restrict__ qkvb)
{
  __shared__ __align__(16) __bf16 vtile[128][72];
  const int bx = blockIdx.x;
  const int mat = bx >> 8, tile = bx & 255, R0 = tile * 64;
  const int m = mat % 3;
  const int t = threadIdx.x, lane = t & 63, wave = t >> 6;
  const int quad = lane >> 4, ln = lane & 15;
  const float* xs = (mat < 3) ? x0 : x1;
  const float* bias = (mat == 0) ? bq0 : (mat == 1) ? bk0 : (mat == 2) ? bv0
                    : (mat == 3) ? bq1 : (mat == 4) ? bk1 : bv1;
  const __bf16* wt = wtb + mat * 16384;
  __bf16* outp = qkvb + (size_t)mat * (ROWS * D_);

  bf16x8 af[4];
  {
    const int row = R0 + wave * 16 + ln;
    #pragma unroll
    for (int ks = 0; ks < 4; ++ks) {
      const float4* xp = (const float4*)(xs + (size_t)row * D_ + ks * 32 + quad * 8);
      float4 a = xp[0], b = xp[1];
      bf16x8 v;
      v[0] = (__bf16)a.x; v[1] = (__bf16)a.y; v[2] = (__bf16)a.z; v[3] = (__bf16)a.w;
      v[4] = (__bf16)b.x; v[5] = (__bf16)b.y; v[6] = (__bf16)b.z; v[7] = (__bf16)b.w;
      af[ks] = v;
    }
  }
  const f32x4 zero4 = {0.f, 0.f, 0.f, 0.f};

  f32x4 acc[8];
  #pragma unroll
  for (int nt = 0; nt < 8; ++nt) acc[nt] = zero4;
  #pragma unroll
  for (int ks = 0; ks < 4; ++ks) {
    #pragma unroll
    for (int nt = 0; nt < 8; ++nt) {
      bf16x8 bfrag = *(const bf16x8*)(wt + (size_t)(nt * 16 + ln) * D_ + ks * 32 + quad * 8);
      acc[nt] = mfma16(af[ks], bfrag, acc[nt]);
    }
  }

  if (m != 2) {
    const float sc = (m == 0) ? SCALE2_ : 1.0f;
    #pragma unroll
    for (int nt = 0; nt < 8; ++nt) {
      const int col = nt * 16 + ln;
      const float bv = bias[col];
      #pragma unroll
      for (int r = 0; r < 4; ++r) {
        float v = fmaxf(acc[nt][r] + bv, 0.f) * sc;
        outp[(size_t)(R0 + wave * 16 + quad * 4 + r) * D_ + col] = (__bf16)v;
      }
    }
  } else {
    #pragma unroll
    for (int nt = 0; nt < 8; ++nt) {
      const int col = nt * 16 + ln;
      const float bv = bias[col];
      #pragma unroll
      for (int r = 0; r < 4; ++r) {
        float v = fmaxf(acc[nt][r] + bv, 0.f);
        vtile[col][wave * 16 + quad * 4 + r] = (__bf16)v;
      }
    }
    __syncthreads();
    const int b = R0 >> 9, kb2 = R0 & 511;
    const int dim = t >> 1, off = (t & 1) * 32;
    uint4* dst = (uint4*)(outp + (size_t)b * (D_ * N_) + (size_t)dim * N_ + kb2 + off);
    const uint4* srcp = (const uint4*)&vtile[dim][off];
    #pragma unroll
    for (int i = 0; i < 4; ++i) dst[i] = srcp[i];
  }
}

// ---------------------------------------------------------------------------
// Kernel 3: fused masked attention + wo projection + relu (no split-K).
// bx: qt = bx>>7, cb = bx&127 (a,b) -> 8 q-tiles of a combo share bx%8 => XCD
// L2 reuse. wave = head h.
// KEY-PERMUTED register pipeline: tile `at` covers keys
//   kappa = 32*(at>>1) + 8*quad + 4*(at&1) + r   (a bijection of the chunk)
// so the S^T C-fragment (P values) in each lane IS the PV B-fragment:
//   pb(s2) = concat(pregs[2*s2], pregs[2*s2+1])  -- no LDS, no barriers,
// no shuffles in the K-loop. K rows and mask bits use the same permutation;
// V / PV unchanged (contraction axis reordering is free).
// 64 q-rows/block, 4 bt streams/wave = the empirically-best ILP shape
// (R10's 32-row variant regressed: less per-wave ILP, 2x K/V load issue).
// ---------------------------------------------------------------------------
__global__ __launch_bounds__(256, 2) void attn_kernel(
    const __bf16* __restrict__ qkvb,
    const unsigned long long* __restrict__ mpk,
    const __bf16* __restrict__ wob,
    const float* __restrict__ bo00, const float* __restrict__ bo01,
    const float* __restrict__ bo10, const float* __restrict__ bo11,
    __bf16* __restrict__ projb)
{
  __shared__ __align__(16) __bf16 OL[64][136];   // epilogue O staging (17408 B)

  const int bx = blockIdx.x;
  const int qt = bx >> 7, cb = bx & 127, a = cb >> 5, b = cb & 31;
  const int t = threadIdx.x, lane = t & 63, h = t >> 6;
  const int quad = lane >> 4, ln = lane & 15;

  const int qg = (a == 1 || a == 3) ? 1 : 0;
  const int kg = (a == 1 || a == 2) ? 1 : 0;
  const float* bo = (a == 0) ? bo00 : (a == 1) ? bo11 : (a == 2) ? bo01 : bo10;

  const __bf16* qb  = qkvb + (size_t)(qg * 3 + 0) * (ROWS * D_) + (size_t)(b * N_ + qt * 64) * D_;
  const __bf16* kb  = qkvb + (size_t)(kg * 3 + 1) * (ROWS * D_) + (size_t)b * N_ * D_;
  const __bf16* vtb = qkvb + (size_t)(kg * 3 + 2) * (ROWS * D_) + (size_t)b * D_ * N_;
  const unsigned long long* mrow = mpk + (size_t)(a * 32 + b) * 8 * 512 + qt * 64;

  // permuted tile-local key row for K loads (position p=ln within a tile)
  const int lnoff = 8 * (ln >> 2) + (ln & 3);

  // Q as MFMA-B fragments (persistent): n = qrow = ln, k = dim quad*8+j
  bf16x8 qf[4];
  #pragma unroll
  for (int bt = 0; bt < 4; ++bt)
    qf[bt] = *(const bf16x8*)(qb + (size_t)(bt * 16 + ln) * D_ + h * 32 + quad * 8);

  const f32x4 zero4 = {0.f, 0.f, 0.f, 0.f};
  f32x4 Oacc[2][4];
  float lp[4];
  #pragma unroll
  for (int bt = 0; bt < 4; ++bt) {
    lp[bt] = 0.f;
    Oacc[0][bt] = zero4; Oacc[1][bt] = zero4;
  }

  unsigned long long mb[4];
  #pragma unroll
  for (int bt = 0; bt < 4; ++bt) mb[bt] = mrow[bt * 16 + ln];

  for (int ch = 0; ch < 8; ++ch) {
    const int kc = ch * 64;

    // prefetch next chunk's mask bits (L2/L3-resident, 4x8B)
    unsigned long long mbn[4] = {0, 0, 0, 0};
    if (ch < 7) {
      #pragma unroll
      for (int bt = 0; bt < 4; ++bt)
        mbn[bt] = mrow[(size_t)(ch + 1) * 512 + bt * 16 + ln];
    }

    // S^T tiles with permuted keys; P kept in registers.
    bf16x4 pregs[4][4];   // [at][bt]
    #pragma unroll
    for (int at = 0; at < 4; ++at) {
      const int kconst = 32 * (at >> 1) + 4 * (at & 1);   // tile key base bits
      bf16x8 kf = *(const bf16x8*)(kb + (size_t)(kc + kconst + lnoff) * D_ + h * 32 + quad * 8);
      #pragma unroll
      for (int bt = 0; bt < 4; ++bt) {
        f32x4 s = mfma16(kf, qf[bt], zero4);
        bf16x4 pv;
        float ps = 0.f;
        #pragma unroll
        for (int r = 0; r < 4; ++r) {
          // global key for (at, quad, r) = kconst + 8*quad + r
          const int bit = (int)((mb[bt] >> (kconst + 8 * quad + r)) & 1ull);
          const float p = bit ? __builtin_amdgcn_exp2f(s[r]) : 0.f;
          ps += p;
          pv[r] = (__bf16)p;
        }
        lp[bt] += ps;
        pregs[at][bt] = pv;
      }
    }

    // O^T += V^T . P^T — P fragments come straight from registers.
    #pragma unroll
    for (int s2 = 0; s2 < 2; ++s2) {
      bf16x8 pb[4];
      #pragma unroll
      for (int bt = 0; bt < 4; ++bt) {
        #pragma unroll
        for (int j = 0; j < 4; ++j) {
          pb[bt][j]     = pregs[2 * s2][bt][j];
          pb[bt][4 + j] = pregs[2 * s2 + 1][bt][j];
        }
      }
      #pragma unroll
      for (int d = 0; d < 2; ++d) {
        bf16x8 vf = *(const bf16x8*)(vtb + (size_t)(h * 32 + d * 16 + ln) * N_ + kc + s2 * 32 + quad * 8);
        #pragma unroll
        for (int bt = 0; bt < 4; ++bt)
          Oacc[d][bt] = mfma16(vf, pb[bt], Oacc[d][bt]);
      }
    }

    #pragma unroll
    for (int bt = 0; bt < 4; ++bt) mb[bt] = mbn[bt];
  }

  float fac[4];
  #pragma unroll
  for (int bt = 0; bt < 4; ++bt) {
    float l = lp[bt] + __shfl_xor(lp[bt], 16);
    l += __shfl_xor(l, 32);
    fac[bt] = (l > 0.f) ? 1.f / l : 0.f;   // l==0: fully-masked row -> 0 (gated)
  }

  // epilogue: O^T regs -> LDS O[row][dim] (packed b64), then wo MFMA
  #pragma unroll
  for (int d = 0; d < 2; ++d)
    #pragma unroll
    for (int bt = 0; bt < 4; ++bt) {
      bf16x4 ov;
      #pragma unroll
      for (int r = 0; r < 4; ++r) ov[r] = (__bf16)(Oacc[d][bt][r] * fac[bt]);
      *(bf16x4*)&OL[bt * 16 + ln][h * 32 + d * 16 + quad * 4] = ov;
    }
  __syncthreads();

  const __bf16* wo = wob + a * 4096;   // [n 32][k 128]
  f32x4 pacc[2];
  pacc[0] = zero4; pacc[1] = zero4;
  #pragma unroll
  for (int ks = 0; ks < 4; ++ks) {
    bf16x8 afr = *(const bf16x8*)&OL[h * 16 + ln][ks * 32 + quad * 8];
    #pragma unroll
    for (int ct = 0; ct < 2; ++ct) {
      bf16x8 bw = *(const bf16x8*)(wo + (size_t)(ct * 16 + ln) * D_ + ks * 32 + quad * 8);
      pacc[ct] = mfma16(afr, bw, pacc[ct]);
    }
  }
  const int R0g = b * N_ + qt * 64;
  #pragma unroll
  for (int ct = 0; ct < 2; ++ct) {
    const int col = ct * 16 + ln;
    const float bv = bo[col];
    #pragma unroll
    for (int r = 0; r < 4; ++r) {
      const float v = fmaxf(pacc[ct][r] + bv, 0.f);
      projb[(size_t)(a * ROWS + R0g + h * 16 + quad * 4 + r) * 32 + col] = (__bf16)v;
    }
  }
}

// ---------------------------------------------------------------------------
// Kernel 4: out_g = concat(inner_g, inter_g) @ wf_g + bf_g  (MFMA, no LDS)
// grid 512: g = bx>>8, 64-row tile = bx&255; wave = 16-row tile.
// ---------------------------------------------------------------------------
__global__ __launch_bounds__(256) void outproj_kernel(
    const __bf16* __restrict__ projb, const __bf16* __restrict__ wfb,
    const float* __restrict__ bf0, const float* __restrict__ bf1,
    float* __restrict__ out)
{
  const int bx = blockIdx.x;
  const int g = bx >> 8, tile = bx & 255;
  const int t = threadIdx.x, lane = t & 63, w = t >> 6;
  const int quad = lane >> 4, ln = lane & 15;
  const int row = tile * 64 + w * 16;
  const f32x4 zero4 = {0.f, 0.f, 0.f, 0.f};

  const float* bfp = g ? bf1 : bf0;
  f32x4 acc[8];
  #pragma unroll
  for (int ct = 0; ct < 8; ++ct) acc[ct] = zero4;
  #pragma unroll
  for (int s = 0; s < 2; ++s) {
    const int asrc = s ? (2 + g) : g;
    bf16x8 afr = *(const bf16x8*)(projb + (size_t)(asrc * ROWS + row + ln) * 32 + quad * 8);
    const __bf16* wb = wfb + g * 8192 + s * 32;
    #pragma unroll
    for (int ct = 0; ct < 8; ++ct) {
      bf16x8 bw = *(const bf16x8*)(wb + (size_t)(ct * 16 + ln) * 64 + quad * 8);
      acc[ct] = mfma16(afr, bw, acc[ct]);
    }
  }
  float* og = out + (size_t)g * (ROWS * D_);
  #pragma unroll
  for (int ct = 0; ct < 8; ++ct) {
    const int col = ct * 16 + ln;
    const float bv = bfp[col];
    #pragma unroll
    for (int r = 0; r < 4; ++r)
      og[(size_t)(row + quad * 4 + r) * D_ + col] = acc[ct][r] + bv;
  }
}

// ---------------------------------------------------------------------------
extern "C" void kernel_launch(void* const* d_in, const int* in_sizes, int n_in,
                              void* d_out, int out_size, void* d_ws, size_t ws_size,
                              hipStream_t stream)
{
  const float* x0 = (const float*)d_in[0];
  const float* x1 = (const float*)d_in[1];
  const int* m00 = (const int*)d_in[2];
  const int* m01 = (const int*)d_in[3];
  const int* m10 = (const int*)d_in[4];
  const int* m11 = (const int*)d_in[5];
  const float* wq0 = (const float*)d_in[6];  const float* bq0 = (const float*)d_in[7];
  const float* wk0 = (const float*)d_in[8];  const float* bk0 = (const float*)d_in[9];
  const float* wv0 = (const float*)d_in[10]; const float* bv0 = (const float*)d_in[11];
  const float* wq1 = (const float*)d_in[12]; const float* bq1 = (const float*)d_in[13];
  const float* wk1 = (const float*)d_in[14]; const float* bk1 = (const float*)d_in[15];
  const float* wv1 = (const float*)d_in[16]; const float* bv1 = (const float*)d_in[17];
  const float* wo00 = (const float*)d_in[18]; const float* bo00 = (const float*)d_in[19];
  const float* wo01 = (const float*)d_in[20]; const float* bo01 = (const float*)d_in[21];
  const float* wo10 = (const float*)d_in[22]; const float* bo10 = (const float*)d_in[23];
  const float* wo11 = (const float*)d_in[24]; const float* bo11 = (const float*)d_in[25];
  const float* wf0 = (const float*)d_in[26]; const float* bf0 = (const float*)d_in[27];
  const float* wf1 = (const float*)d_in[28]; const float* bf1 = (const float*)d_in[29];

  // workspace layout (bytes):
  //   qkvb  @ 0        : 6 * 16384*128 * 2 = 25165824
  //   projb @ 25165824 : 4 * 16384*32 * 2  =  4194304
  //   wtb   @ 29360128 : 6 * 128*128 * 2   =   196608
  //   wob   @ 29556736 : 4 * 32*128 * 2    =    32768
  //   wfb   @ 29589504 : 2 * 128*64 * 2    =    32768
  //   mpk   @ 29622272 : 4*32*8*512 * 8    =  4194304   (total ~33.8 MB)
  __bf16* qkvb = (__bf16*)d_ws;
  __bf16* projb = (__bf16*)((char*)d_ws + 25165824);
  __bf16* wtb  = (__bf16*)((char*)d_ws + 29360128);
  __bf16* wob  = (__bf16*)((char*)d_ws + 29556736);
  __bf16* wfb  = (__bf16*)((char*)d_ws + 29589504);
  unsigned long long* mpk = (unsigned long long*)((char*)d_ws + 29622272);

  prep_kernel<<<dim3(16512), dim3(256), 0, stream>>>(
      m00, m01, m10, m11, wq0, wk0, wv0, wq1, wk1, wv1,
      wo00, wo01, wo10, wo11, wf0, wf1, wtb, wob, wfb, mpk);
  qkv_kernel<<<dim3(1536), dim3(256), 0, stream>>>(
      x0, x1, bq0, bk0, bv0, bq1, bk1, bv1, wtb, qkvb);
  attn_kernel<<<dim3(1024), dim3(256), 0, stream>>>(
      qkvb, mpk, wob, bo00, bo01, bo10, bo11, projb);
  outproj_kernel<<<dim3(512), dim3(256), 0, stream>>>(
      projb, wfb, bf0, bf1, (float*)d_out);
}